// Round 15
// baseline (212.188 us; speedup 1.0000x reference)
//
#include <hip/hip_runtime.h>
#include <hip/hip_fp16.h>
#include <cstdint>
#include <cstddef>

typedef _Float16 f16;
typedef _Float16 f16x8 __attribute__((ext_vector_type(8)));
typedef _Float16 f16x4 __attribute__((ext_vector_type(4)));
typedef float    f32x4 __attribute__((ext_vector_type(4)));

#define MFMA(a, b, c) __builtin_amdgcn_mfma_f32_16x16x32_f16(a, b, c, 0, 0, 0)

// B=4, S=2048, D=1024, H=16, KS=VS=64, O=1024.

__device__ __forceinline__ void gload_lds16(const f16* g, f16* l) {
    __builtin_amdgcn_global_load_lds(
        (const __attribute__((address_space(1))) void*)g,
        (__attribute__((address_space(3))) void*)l, 16, 0, 0);
}

// ------------------- fp32 -> fp16 convert (Q,K,V fused) ----------------------
__global__ void k_convert3(const float* __restrict__ Q, const float* __restrict__ K,
                           const float* __restrict__ V, f16* __restrict__ Qh,
                           f16* __restrict__ Kh, f16* __restrict__ Vh) {
    const int seg = blockIdx.x >> 11;              // 0..2 (2048 blocks each)
    const int lb  = blockIdx.x & 2047;
    const float* src = seg == 0 ? Q : (seg == 1 ? K : V);
    f16* dst = seg == 0 ? Qh : (seg == 1 ? Kh : Vh);
    int i = lb * blockDim.x + threadIdx.x;
    for (; i < 2097152; i += 524288) {             // n4 = 8192*1024/4
        float4 v = ((const float4*)src)[i];
        f16x4 h;
        h[0] = (f16)v.x; h[1] = (f16)v.y; h[2] = (f16)v.z; h[3] = (f16)v.w;
        ((f16x4*)dst)[i] = h;
    }
}

// ---------------- weight transpose + convert to fp16 (all 4 fused) ----------
// widx 0,1,2: W[H=16][D=1024][KS=64] -> WT + widx*1M, rows n=h*64+ks, cols d
// widx 3:     Wo[K=1024][N=1024]     -> WoT[n][k]
__global__ void k_transpose_all(const float* __restrict__ Wq, const float* __restrict__ Wk,
                                const float* __restrict__ Wv, const float* __restrict__ Wo,
                                f16* __restrict__ WT, f16* __restrict__ WoT) {
    __shared__ float T[64][65];
    const int bx = blockIdx.x;
    const int widx = bx >> 8, sub = bx & 255;
    const int nb = sub >> 4, db = sub & 15;
    const int tid = threadIdx.x;
    const float* W = widx == 0 ? Wq : (widx == 1 ? Wk : (widx == 2 ? Wv : Wo));
    f16* Wt = (widx < 3) ? (WT + (size_t)widx * 1048576) : WoT;
    const float* src = (widx < 3) ? (W + nb * 65536 + db * 4096)
                                  : (W + db * 65536 + nb * 64);
    const int rstride = (widx < 3) ? 64 : 1024;
    {
        int nn = tid & 63, d0 = tid >> 6;
#pragma unroll
        for (int p = 0; p < 16; ++p) {
            int dd = p * 4 + d0;
            T[dd][nn] = src[dd * rstride + nn];
        }
    }
    __syncthreads();
    {
        int dd = tid & 63, n0 = tid >> 6;
#pragma unroll
        for (int p = 0; p < 16; ++p) {
            int nn = p * 4 + n0;
            Wt[(size_t)(nb * 64 + nn) * 1024 + db * 64 + dd] = (f16)T[dd][nn];
        }
    }
}

// --------------------------- fused q/k/v GEMM --------------------------------
// blockIdx.y 0..23: seg = y>>3 (0=q,1=k,2=v), col-block = y&7.
// seg 0: q head-major [(bh)][s][64], scaled by SC
// seg 1: K tile-packed LANE-MAJOR PERMUTED:
//        [bh][tile][frag: t*512+half*1024][(lgf*16+lrf)*8+j] holds
//        K[p=t*16+lrf][d=half*32+lgf*8+j], p = perm(ks5)
// seg 2: V^T tile-packed LANE-MAJOR: [bh][tile][m*512][(lgf*16+lrf)*8+j] holds
//        V^T[vd=m*16+lrf][ks=lgf*8+j]
// (lane-major: LDS stage AND fragment reads are both linear -> 0 bank conflicts)
__global__ __launch_bounds__(256) void k_gemm_qkv(
    const f16* __restrict__ Qh, const f16* __restrict__ Kh, const f16* __restrict__ Vh,
    const f16* __restrict__ WT, const float* __restrict__ bq,
    const float* __restrict__ bk, const float* __restrict__ bv,
    f16* __restrict__ qout, f16* __restrict__ kout, f16* __restrict__ vout, float SC) {
    __shared__ f16 As[128 * 32];
    __shared__ f16 Bs[128 * 32];
    const int yy = blockIdx.y;
    const int seg = yy >> 3;
    const f16* A    = seg == 0 ? Qh : (seg == 1 ? Kh : Vh);
    const f16* Bt   = WT + (size_t)seg * 1048576;
    const float* bias = seg == 0 ? bq : (seg == 1 ? bk : bv);
    const float scale = seg == 0 ? SC : 1.0f;

    const int tid = threadIdx.x;
    const int wid = tid >> 6, lane = tid & 63;
    const int wr = wid >> 1, wc = wid & 1;
    const int lr = lane & 15, lg = lane >> 4;
    const int row0 = blockIdx.x * 128, col0 = (yy & 7) * 128;

    f32x4 acc[4][4];
#pragma unroll
    for (int m = 0; m < 4; ++m)
#pragma unroll
        for (int n = 0; n < 4; ++n) acc[m][n] = (f32x4){0.f, 0.f, 0.f, 0.f};

    const int c0 = tid, c1 = tid + 256;
    const int r0 = c0 >> 2, cb0 = (c0 & 3) * 8;
    const int r1 = c1 >> 2, cb1 = (c1 & 3) * 8;

    for (int k0 = 0; k0 < 1024; k0 += 32) {
        __syncthreads();
        gload_lds16(&A[(size_t)(row0 + r0) * 1024 + k0 + cb0], &As[c0 * 8]);
        gload_lds16(&Bt[(size_t)(col0 + r0) * 1024 + k0 + cb0], &Bs[c0 * 8]);
        gload_lds16(&A[(size_t)(row0 + r1) * 1024 + k0 + cb1], &As[c1 * 8]);
        gload_lds16(&Bt[(size_t)(col0 + r1) * 1024 + k0 + cb1], &Bs[c1 * 8]);
        __syncthreads();
        f16x8 af[4], bf[4];
#pragma unroll
        for (int m = 0; m < 4; ++m) af[m] = *(const f16x8*)&As[(wr * 64 + m * 16 + lr) * 32 + lg * 8];
#pragma unroll
        for (int n = 0; n < 4; ++n) bf[n] = *(const f16x8*)&Bs[(wc * 64 + n * 16 + lr) * 32 + lg * 8];
#pragma unroll
        for (int m = 0; m < 4; ++m)
#pragma unroll
            for (int n = 0; n < 4; ++n) acc[m][n] = MFMA(af[m], bf[n], acc[m][n]);
    }

#pragma unroll
    for (int m = 0; m < 4; ++m) {
#pragma unroll
        for (int n = 0; n < 4; ++n) {
            int col = col0 + wc * 64 + n * 16 + lr;
            float bv_ = bias[col];
            int rowb = row0 + wr * 64 + m * 16 + lg * 4;
            int srow = rowb & 2047;
            if (seg == 0) {
#pragma unroll
                for (int r = 0; r < 4; ++r) {
                    int row = rowb + r;
                    size_t a = ((size_t)((row >> 11) * 16 + (col >> 6)) * 2048 + (row & 2047)) * 64 + (col & 63);
                    qout[a] = (f16)((acc[m][n][r] + bv_) * scale);
                }
            } else if (seg == 1) {
                // K lane-major: kpos = srow (p = perm(ks5)), d = col&63
                int ks5 = srow & 31;
                int p0 = ((ks5 >> 2) & 1) * 16 + (ks5 >> 3) * 4 + (ks5 & 3);  // p0&3 == 0
                size_t abase = (size_t)((rowb >> 11) * 16 + (col >> 6)) * 131072
                             + (size_t)(srow >> 5) * 2048
                             + (size_t)(p0 >> 4) * 512            // t
                             + (size_t)((col & 63) >> 5) * 1024   // half
                             + (size_t)((col & 31) >> 3) * 128    // lgf*16*8
                             + (col & 7);                          // j
#pragma unroll
                for (int r = 0; r < 4; ++r)
                    kout[abase + (size_t)((p0 & 15) + r) * 8] = (f16)(acc[m][n][r] + bv_);
            } else {
                // V lane-major: vd = col&63, ks = srow&31; r -> consecutive j
                size_t a = (size_t)((rowb >> 11) * 16 + (col >> 6)) * 131072
                         + (size_t)(srow >> 5) * 2048
                         + (size_t)((col & 63) >> 4) * 512        // m
                         + (size_t)((srow & 31) >> 3) * 128       // lgf*16*8
                         + (size_t)(col & 15) * 8                 // lrf*8
                         + (srow & 7);                            // j0 (0 or 4)
                f16x4 ov;
#pragma unroll
                for (int r = 0; r < 4; ++r) ov[r] = (f16)(acc[m][n][r] + bv_);
                *(f16x4*)&vout[a] = ov;
            }
        }
    }
}

// ------------------------------ output GEMM ----------------------------------
__global__ __launch_bounds__(256) void k_gemm_out(const f16* __restrict__ A,
                                                  const f16* __restrict__ Bt,
                                                  const float* __restrict__ bias,
                                                  float* __restrict__ Cout) {
    __shared__ f16 As[128 * 32];
    __shared__ f16 Bs[128 * 32];
    const int tid = threadIdx.x;
    const int wid = tid >> 6, lane = tid & 63;
    const int wr = wid >> 1, wc = wid & 1;
    const int lr = lane & 15, lg = lane >> 4;
    const int row0 = blockIdx.x * 128, col0 = blockIdx.y * 128;

    f32x4 acc[4][4];
#pragma unroll
    for (int m = 0; m < 4; ++m)
#pragma unroll
        for (int n = 0; n < 4; ++n) acc[m][n] = (f32x4){0.f, 0.f, 0.f, 0.f};

    const int c0 = tid, c1 = tid + 256;
    const int r0 = c0 >> 2, cb0 = (c0 & 3) * 8;
    const int r1 = c1 >> 2, cb1 = (c1 & 3) * 8;

    for (int k0 = 0; k0 < 1024; k0 += 32) {
        __syncthreads();
        gload_lds16(&A[(size_t)(row0 + r0) * 1024 + k0 + cb0], &As[c0 * 8]);
        gload_lds16(&Bt[(size_t)(col0 + r0) * 1024 + k0 + cb0], &Bs[c0 * 8]);
        gload_lds16(&A[(size_t)(row0 + r1) * 1024 + k0 + cb1], &As[c1 * 8]);
        gload_lds16(&Bt[(size_t)(col0 + r1) * 1024 + k0 + cb1], &Bs[c1 * 8]);
        __syncthreads();
        f16x8 af[4], bf[4];
#pragma unroll
        for (int m = 0; m < 4; ++m) af[m] = *(const f16x8*)&As[(wr * 64 + m * 16 + lr) * 32 + lg * 8];
#pragma unroll
        for (int n = 0; n < 4; ++n) bf[n] = *(const f16x8*)&Bs[(wc * 64 + n * 16 + lr) * 32 + lg * 8];
#pragma unroll
        for (int m = 0; m < 4; ++m)
#pragma unroll
            for (int n = 0; n < 4; ++n) acc[m][n] = MFMA(af[m], bf[n], acc[m][n]);
    }

#pragma unroll
    for (int m = 0; m < 4; ++m) {
#pragma unroll
        for (int n = 0; n < 4; ++n) {
            int col = col0 + wc * 64 + n * 16 + lr;
            float bv = bias[col];
#pragma unroll
            for (int r = 0; r < 4; ++r) {
                int row = row0 + wr * 64 + m * 16 + lg * 4 + r;
                Cout[(size_t)row * 1024 + col] = acc[m][n][r] + bv;
            }
        }
    }
}

// ------------------------------ attention -----------------------------------
// LDS-staged, lane-major fragments (0 bank conflicts, round 14). NEW: 4-buffer
// staging with ONE barrier per 2 tiles (round-14 diagnosis: elapsed ~3450
// cy/iter vs ~1750 cy of pipe work — the per-tile __syncthreads vmcnt(0)
// drain + 4-wave convergence was the stall). Pair loop: stage tiles t+2,t+3
// at pair start (they have 2 full tiles of compute to land before the drain),
// compute tiles t,t+1 from buffers staged one pair ago, barrier once.
// s_setprio REMOVED: block is barrier-synced lockstep = m190's regime where
// setprio measured negative. Compute body is a textual macro (no lambdas /
// pointer-passed register arrays — round-9 spill lesson).
#define ATTN_TILE(Kc, Vc)                                                     \
    do {                                                                      \
        f16x8 ka0 = *(const f16x8*)&(Kc)[fo];                                 \
        f16x8 ka1 = *(const f16x8*)&(Kc)[fo + 1024];                          \
        f16x8 ka2 = *(const f16x8*)&(Kc)[fo + 512];                           \
        f16x8 ka3 = *(const f16x8*)&(Kc)[fo + 1536];                          \
        f32x4 st[2][2];                                                       \
        _Pragma("unroll")                                                     \
        for (int qt = 0; qt < 2; ++qt) {                                      \
            float nm = -m_r[qt];                                              \
            f32x4 z = (f32x4){nm, nm, nm, nm};                                \
            z = MFMA(ka0, qf[qt][0], z);                                      \
            z = MFMA(ka1, qf[qt][1], z);                                      \
            st[qt][0] = z;                                                    \
            f32x4 z2 = (f32x4){nm, nm, nm, nm};                               \
            z2 = MFMA(ka2, qf[qt][0], z2);                                    \
            z2 = MFMA(ka3, qf[qt][1], z2);                                    \
            st[qt][1] = z2;                                                   \
        }                                                                     \
        f16x8 vv0 = *(const f16x8*)&(Vc)[fo];                                 \
        f16x8 vv1 = *(const f16x8*)&(Vc)[fo + 512];                           \
        f16x8 vv2 = *(const f16x8*)&(Vc)[fo + 1024];                          \
        f16x8 vv3 = *(const f16x8*)&(Vc)[fo + 1536];                          \
        {                                                                     \
            float lm[2];                                                      \
            _Pragma("unroll")                                                 \
            for (int qt = 0; qt < 2; ++qt) {                                  \
                float a0 = fmaxf(fmaxf(st[qt][0][0], st[qt][0][1]), st[qt][0][2]); \
                float b0 = fmaxf(fmaxf(st[qt][0][3], st[qt][1][0]), st[qt][1][1]); \
                float c0 = fmaxf(fmaxf(st[qt][1][2], st[qt][1][3]), a0);      \
                lm[qt] = fmaxf(b0, c0);                                       \
            }                                                                 \
            if (__any((lm[0] > THR) || (lm[1] > THR))) {                      \
                _Pragma("unroll")                                             \
                for (int qt = 0; qt < 2; ++qt) {                              \
                    float t0 = lm[qt];                                        \
                    t0 = fmaxf(t0, __shfl_xor(t0, 16, 64));                   \
                    t0 = fmaxf(t0, __shfl_xor(t0, 32, 64));                   \
                    float delta = fmaxf(0.f, t0);                             \
                    float alpha = __builtin_amdgcn_exp2f(-delta);             \
                    _Pragma("unroll")                                         \
                    for (int m = 0; m < 4; ++m)                               \
                        _Pragma("unroll")                                     \
                        for (int r = 0; r < 4; ++r) o[qt][m][r] *= alpha;     \
                    l_p[qt] *= alpha;                                         \
                    m_r[qt] += delta;                                         \
                    _Pragma("unroll")                                         \
                    for (int t = 0; t < 2; ++t)                               \
                        _Pragma("unroll")                                     \
                        for (int r = 0; r < 4; ++r) st[qt][t][r] -= delta;    \
                }                                                             \
            }                                                                 \
        }                                                                     \
        f16x8 pf[2];                                                          \
        _Pragma("unroll")                                                     \
        for (int qt = 0; qt < 2; ++qt) {                                      \
            float ps = 0.f;                                                   \
            union { uint32_t u[4]; f16x8 v; } bb;                             \
            _Pragma("unroll")                                                 \
            for (int t = 0; t < 2; ++t)                                       \
                _Pragma("unroll")                                             \
                for (int pr = 0; pr < 2; ++pr) {                              \
                    float e0 = __builtin_amdgcn_exp2f(st[qt][t][2 * pr]);     \
                    float e1 = __builtin_amdgcn_exp2f(st[qt][t][2 * pr + 1]); \
                    ps += e0 + e1;                                            \
                    auto hp = __builtin_amdgcn_cvt_pkrtz(e0, e1);             \
                    bb.u[t * 2 + pr] = __builtin_bit_cast(uint32_t, hp);      \
                }                                                             \
            l_p[qt] += ps;                                                    \
            pf[qt] = bb.v;                                                    \
        }                                                                     \
        _Pragma("unroll")                                                     \
        for (int qt = 0; qt < 2; ++qt) {                                      \
            o[qt][0] = MFMA(vv0, pf[qt], o[qt][0]);                           \
            o[qt][1] = MFMA(vv1, pf[qt], o[qt][1]);                           \
            o[qt][2] = MFMA(vv2, pf[qt], o[qt][2]);                           \
            o[qt][3] = MFMA(vv3, pf[qt], o[qt][3]);                           \
        }                                                                     \
    } while (0)

__global__ __launch_bounds__(256, 4) void k_attn(const f16* __restrict__ q,
                                                 const f16* __restrict__ k2,
                                                 const f16* __restrict__ v2,
                                                 f16* __restrict__ cat) {
    const int g = blockIdx.x;                 // 0..1023
    const int xcd = g & 7, i = g >> 3;        // i: 0..127
    const int bh = xcd * 8 + (i >> 4);        // 8 bh per XCD (K/V L2 locality)
    const int qb = i & 15;                    // 16 q-blocks of 128 rows
    const int b = bh >> 4, h = bh & 15;

    const int tid = threadIdx.x, wid = tid >> 6, lane = tid & 63;
    const int lr = lane & 15, lg = lane >> 4;
    const int qw = qb * 128 + wid * 32;       // this wave's first q-row

    __shared__ f16 Ks[4][2048];
    __shared__ f16 Vs[4][2048];

    const float THR = 8.0f;

    // Q fragments (hoisted; pre-scaled by 1/8*log2e in the q GEMM)
    f16x8 qf[2][2];
#pragma unroll
    for (int qt = 0; qt < 2; ++qt)
#pragma unroll
        for (int hf = 0; hf < 2; ++hf)
            qf[qt][hf] = *(const f16x8*)&q[((size_t)bh * 2048 + qw + qt * 16 + lr) * 64 + hf * 32 + lg * 8];

    const f16* kt = k2 + (size_t)bh * 131072;     // tile stride 2048 elements
    const f16* vt = v2 + (size_t)bh * 131072;
    const int so = tid * 8;                       // stage offset (16B/thread)
    const int fo = lane * 8;                      // lane-major fragment offset

    f32x4 o[2][4];
#pragma unroll
    for (int qt = 0; qt < 2; ++qt)
#pragma unroll
        for (int m = 0; m < 4; ++m) o[qt][m] = (f32x4){0.f, 0.f, 0.f, 0.f};
    float m_r[2] = {0.f, 0.f}, l_p[2] = {0.f, 0.f};

    // prologue: stage tiles 0,1 into buffers 0,1
    gload_lds16(kt + so, &Ks[0][so]);
    gload_lds16(vt + so, &Vs[0][so]);
    gload_lds16(kt + 2048 + so, &Ks[1][so]);
    gload_lds16(vt + 2048 + so, &Vs[1][so]);
    __syncthreads();

    // pair loop: tiles (2pp, 2pp+1); stage (2pp+2, 2pp+3); ONE barrier per pair
    for (int pp = 0; pp < 32; ++pp) {
        const int t0 = 2 * pp;
        const int ba = t0 & 3, bb2 = (t0 + 1) & 3;
        const int bc = (t0 + 2) & 3, bd = (t0 + 3) & 3;

        // stage next pair (pp=31 reads 2 tiles past this bh's kb2/vb2 range:
        // next-bh data / adjacent ws buffer — in-bounds of d_ws, never consumed)
        gload_lds16(kt + (size_t)(t0 + 2) * 2048 + so, &Ks[bc][so]);
        gload_lds16(vt + (size_t)(t0 + 2) * 2048 + so, &Vs[bc][so]);
        gload_lds16(kt + (size_t)(t0 + 3) * 2048 + so, &Ks[bd][so]);
        gload_lds16(vt + (size_t)(t0 + 3) * 2048 + so, &Vs[bd][so]);

        ATTN_TILE(&Ks[ba][0], &Vs[ba][0]);
        ATTN_TILE(&Ks[bb2][0], &Vs[bb2][0]);

        __syncthreads();   // buffer handoff: drains stage (covered by 2 tiles)
    }

    // epilogue: reduce per-lane l partials, normalize, store
#pragma unroll
    for (int qt = 0; qt < 2; ++qt) {
        float l = l_p[qt];
        l += __shfl_xor(l, 16, 64);
        l += __shfl_xor(l, 32, 64);
        float inv = 1.f / l;
        size_t cb = ((size_t)b * 2048 + qw + qt * 16 + lr) * 1024 + h * 64 + lg * 4;
#pragma unroll
        for (int m = 0; m < 4; ++m) {
            f16x4 ov;
#pragma unroll
            for (int r = 0; r < 4; ++r) ov[r] = (f16)(o[qt][m][r] * inv);
            *(f16x4*)&cat[cb + m * 16] = ov;
        }
    }
}

// ---------------------------------------------------------------------------
extern "C" void kernel_launch(void* const* d_in, const int* in_sizes, int n_in,
                              void* d_out, int out_size, void* d_ws, size_t ws_size,
                              hipStream_t stream) {
    const float* Q  = (const float*)d_in[0];
    const float* K  = (const float*)d_in[1];
    const float* V  = (const float*)d_in[2];
    const float* Wq = (const float*)d_in[3];
    const float* bq = (const float*)d_in[4];
    const float* Wk = (const float*)d_in[5];
    const float* bk = (const float*)d_in[6];
    const float* Wv = (const float*)d_in[7];
    const float* bv = (const float*)d_in[8];
    const float* Wo = (const float*)d_in[9];
    const float* bo = (const float*)d_in[10];

    char* ws = (char*)d_ws;
    size_t off = 0;
    auto alloc = [&](size_t bytes) {
        char* p = ws + off;
        off += (bytes + 255) & ~(size_t)255;
        return p;
    };
    f16* Qh  = (f16*)alloc(8192ULL * 1024 * 2);
    f16* Kh  = (f16*)alloc(8192ULL * 1024 * 2);
    f16* Vh  = (f16*)alloc(8192ULL * 1024 * 2);
    f16* WT  = (f16*)alloc(3ULL * 1024 * 1024 * 2);   // WqT|WkT|WvT contiguous
    f16* WoT = (f16*)alloc(1024ULL * 1024 * 2);
    f16* qb  = (f16*)alloc(8192ULL * 1024 * 2);   // head-major [(b,h)][s][64]
    f16* kb2 = (f16*)alloc(8192ULL * 1024 * 2);   // [bh][tile] lane-major perm K
    f16* vb2 = (f16*)alloc(8192ULL * 1024 * 2);   // [bh][tile] lane-major V^T
    f16* cat = (f16*)alloc(8192ULL * 1024 * 2);   // [B*S][H*VS]

    k_convert3<<<6144, 256, 0, stream>>>(Q, K, V, Qh, Kh, Vh);
    k_transpose_all<<<1024, 256, 0, stream>>>(Wq, Wk, Wv, Wo, WT, WoT);

    const float SC = 0.125f * 1.44269504089f;   // 1/sqrt(64) * log2(e), folded into q
    k_gemm_qkv<<<dim3(64, 24), 256, 0, stream>>>(Qh, Kh, Vh, WT, bq, bk, bv,
                                                 qb, kb2, vb2, SC);

    k_attn<<<1024, 256, 0, stream>>>(qb, kb2, vb2, cat);

    k_gemm_out<<<dim3(64, 8), 256, 0, stream>>>(cat, WoT, bo, (float*)d_out);
}

// Round 16
// 211.556 us; speedup vs baseline: 1.0030x; 1.0030x over previous
//
#include <hip/hip_runtime.h>
#include <hip/hip_fp16.h>
#include <cstdint>
#include <cstddef>

typedef _Float16 f16;
typedef _Float16 f16x8 __attribute__((ext_vector_type(8)));
typedef _Float16 f16x4 __attribute__((ext_vector_type(4)));
typedef float    f32x4 __attribute__((ext_vector_type(4)));

#define MFMA(a, b, c) __builtin_amdgcn_mfma_f32_16x16x32_f16(a, b, c, 0, 0, 0)

// B=4, S=2048, D=1024, H=16, KS=VS=64, O=1024.

__device__ __forceinline__ void gload_lds16(const f16* g, f16* l) {
    __builtin_amdgcn_global_load_lds(
        (const __attribute__((address_space(1))) void*)g,
        (__attribute__((address_space(3))) void*)l, 16, 0, 0);
}

// ------------------- fp32 -> fp16 convert (Q,K,V fused) ----------------------
__global__ void k_convert3(const float* __restrict__ Q, const float* __restrict__ K,
                           const float* __restrict__ V, f16* __restrict__ Qh,
                           f16* __restrict__ Kh, f16* __restrict__ Vh) {
    const int seg = blockIdx.x >> 11;              // 0..2 (2048 blocks each)
    const int lb  = blockIdx.x & 2047;
    const float* src = seg == 0 ? Q : (seg == 1 ? K : V);
    f16* dst = seg == 0 ? Qh : (seg == 1 ? Kh : Vh);
    int i = lb * blockDim.x + threadIdx.x;
    for (; i < 2097152; i += 524288) {             // n4 = 8192*1024/4
        float4 v = ((const float4*)src)[i];
        f16x4 h;
        h[0] = (f16)v.x; h[1] = (f16)v.y; h[2] = (f16)v.z; h[3] = (f16)v.w;
        ((f16x4*)dst)[i] = h;
    }
}

// ---------------- weight transpose + convert to fp16 (all 4 fused) ----------
// widx 0,1,2: W[H=16][D=1024][KS=64] -> WT + widx*1M, rows n=h*64+ks, cols d
// widx 3:     Wo[K=1024][N=1024]     -> WoT[n][k]
__global__ void k_transpose_all(const float* __restrict__ Wq, const float* __restrict__ Wk,
                                const float* __restrict__ Wv, const float* __restrict__ Wo,
                                f16* __restrict__ WT, f16* __restrict__ WoT) {
    __shared__ float T[64][65];
    const int bx = blockIdx.x;
    const int widx = bx >> 8, sub = bx & 255;
    const int nb = sub >> 4, db = sub & 15;
    const int tid = threadIdx.x;
    const float* W = widx == 0 ? Wq : (widx == 1 ? Wk : (widx == 2 ? Wv : Wo));
    f16* Wt = (widx < 3) ? (WT + (size_t)widx * 1048576) : WoT;
    const float* src = (widx < 3) ? (W + nb * 65536 + db * 4096)
                                  : (W + db * 65536 + nb * 64);
    const int rstride = (widx < 3) ? 64 : 1024;
    {
        int nn = tid & 63, d0 = tid >> 6;
#pragma unroll
        for (int p = 0; p < 16; ++p) {
            int dd = p * 4 + d0;
            T[dd][nn] = src[dd * rstride + nn];
        }
    }
    __syncthreads();
    {
        int dd = tid & 63, n0 = tid >> 6;
#pragma unroll
        for (int p = 0; p < 16; ++p) {
            int nn = p * 4 + n0;
            Wt[(size_t)(nb * 64 + nn) * 1024 + db * 64 + dd] = (f16)T[dd][nn];
        }
    }
}

// --------------------------- fused q/k/v GEMM --------------------------------
// blockIdx.y 0..23: seg = y>>3 (0=q,1=k,2=v), col-block = y&7.
// seg 0: q head-major [(bh)][s][64], scaled by SC
// seg 1: K tile-packed LANE-MAJOR PERMUTED:
//        [bh][tile][frag: t*512+half*1024][(lgf*16+lrf)*8+j] holds
//        K[p=t*16+lrf][d=half*32+lgf*8+j], p = perm(ks5)
// seg 2: V^T tile-packed LANE-MAJOR: [bh][tile][m*512][(lgf*16+lrf)*8+j] holds
//        V^T[vd=m*16+lrf][ks=lgf*8+j]
// (lane-major: LDS stage AND fragment reads are both linear -> 0 bank conflicts)
__global__ __launch_bounds__(256) void k_gemm_qkv(
    const f16* __restrict__ Qh, const f16* __restrict__ Kh, const f16* __restrict__ Vh,
    const f16* __restrict__ WT, const float* __restrict__ bq,
    const float* __restrict__ bk, const float* __restrict__ bv,
    f16* __restrict__ qout, f16* __restrict__ kout, f16* __restrict__ vout, float SC) {
    __shared__ f16 As[128 * 32];
    __shared__ f16 Bs[128 * 32];
    const int yy = blockIdx.y;
    const int seg = yy >> 3;
    const f16* A    = seg == 0 ? Qh : (seg == 1 ? Kh : Vh);
    const f16* Bt   = WT + (size_t)seg * 1048576;
    const float* bias = seg == 0 ? bq : (seg == 1 ? bk : bv);
    const float scale = seg == 0 ? SC : 1.0f;

    const int tid = threadIdx.x;
    const int wid = tid >> 6, lane = tid & 63;
    const int wr = wid >> 1, wc = wid & 1;
    const int lr = lane & 15, lg = lane >> 4;
    const int row0 = blockIdx.x * 128, col0 = (yy & 7) * 128;

    f32x4 acc[4][4];
#pragma unroll
    for (int m = 0; m < 4; ++m)
#pragma unroll
        for (int n = 0; n < 4; ++n) acc[m][n] = (f32x4){0.f, 0.f, 0.f, 0.f};

    const int c0 = tid, c1 = tid + 256;
    const int r0 = c0 >> 2, cb0 = (c0 & 3) * 8;
    const int r1 = c1 >> 2, cb1 = (c1 & 3) * 8;

    for (int k0 = 0; k0 < 1024; k0 += 32) {
        __syncthreads();
        gload_lds16(&A[(size_t)(row0 + r0) * 1024 + k0 + cb0], &As[c0 * 8]);
        gload_lds16(&Bt[(size_t)(col0 + r0) * 1024 + k0 + cb0], &Bs[c0 * 8]);
        gload_lds16(&A[(size_t)(row0 + r1) * 1024 + k0 + cb1], &As[c1 * 8]);
        gload_lds16(&Bt[(size_t)(col0 + r1) * 1024 + k0 + cb1], &Bs[c1 * 8]);
        __syncthreads();
        f16x8 af[4], bf[4];
#pragma unroll
        for (int m = 0; m < 4; ++m) af[m] = *(const f16x8*)&As[(wr * 64 + m * 16 + lr) * 32 + lg * 8];
#pragma unroll
        for (int n = 0; n < 4; ++n) bf[n] = *(const f16x8*)&Bs[(wc * 64 + n * 16 + lr) * 32 + lg * 8];
#pragma unroll
        for (int m = 0; m < 4; ++m)
#pragma unroll
            for (int n = 0; n < 4; ++n) acc[m][n] = MFMA(af[m], bf[n], acc[m][n]);
    }

#pragma unroll
    for (int m = 0; m < 4; ++m) {
#pragma unroll
        for (int n = 0; n < 4; ++n) {
            int col = col0 + wc * 64 + n * 16 + lr;
            float bv_ = bias[col];
            int rowb = row0 + wr * 64 + m * 16 + lg * 4;
            int srow = rowb & 2047;
            if (seg == 0) {
#pragma unroll
                for (int r = 0; r < 4; ++r) {
                    int row = rowb + r;
                    size_t a = ((size_t)((row >> 11) * 16 + (col >> 6)) * 2048 + (row & 2047)) * 64 + (col & 63);
                    qout[a] = (f16)((acc[m][n][r] + bv_) * scale);
                }
            } else if (seg == 1) {
                // K lane-major: kpos = srow (p = perm(ks5)), d = col&63
                int ks5 = srow & 31;
                int p0 = ((ks5 >> 2) & 1) * 16 + (ks5 >> 3) * 4 + (ks5 & 3);  // p0&3 == 0
                size_t abase = (size_t)((rowb >> 11) * 16 + (col >> 6)) * 131072
                             + (size_t)(srow >> 5) * 2048
                             + (size_t)(p0 >> 4) * 512            // t
                             + (size_t)((col & 63) >> 5) * 1024   // half
                             + (size_t)((col & 31) >> 3) * 128    // lgf*16*8
                             + (col & 7);                          // j
#pragma unroll
                for (int r = 0; r < 4; ++r)
                    kout[abase + (size_t)((p0 & 15) + r) * 8] = (f16)(acc[m][n][r] + bv_);
            } else {
                // V lane-major: vd = col&63, ks = srow&31; r -> consecutive j
                size_t a = (size_t)((rowb >> 11) * 16 + (col >> 6)) * 131072
                         + (size_t)(srow >> 5) * 2048
                         + (size_t)((col & 63) >> 4) * 512        // m
                         + (size_t)((srow & 31) >> 3) * 128       // lgf*16*8
                         + (size_t)(col & 15) * 8                 // lrf*8
                         + (srow & 7);                            // j0 (0 or 4)
                f16x4 ov;
#pragma unroll
                for (int r = 0; r < 4; ++r) ov[r] = (f16)(acc[m][n][r] + bv_);
                *(f16x4*)&vout[a] = ov;
            }
        }
    }
}

// ------------------------------ output GEMM ----------------------------------
__global__ __launch_bounds__(256) void k_gemm_out(const f16* __restrict__ A,
                                                  const f16* __restrict__ Bt,
                                                  const float* __restrict__ bias,
                                                  float* __restrict__ Cout) {
    __shared__ f16 As[128 * 32];
    __shared__ f16 Bs[128 * 32];
    const int tid = threadIdx.x;
    const int wid = tid >> 6, lane = tid & 63;
    const int wr = wid >> 1, wc = wid & 1;
    const int lr = lane & 15, lg = lane >> 4;
    const int row0 = blockIdx.x * 128, col0 = blockIdx.y * 128;

    f32x4 acc[4][4];
#pragma unroll
    for (int m = 0; m < 4; ++m)
#pragma unroll
        for (int n = 0; n < 4; ++n) acc[m][n] = (f32x4){0.f, 0.f, 0.f, 0.f};

    const int c0 = tid, c1 = tid + 256;
    const int r0 = c0 >> 2, cb0 = (c0 & 3) * 8;
    const int r1 = c1 >> 2, cb1 = (c1 & 3) * 8;

    for (int k0 = 0; k0 < 1024; k0 += 32) {
        __syncthreads();
        gload_lds16(&A[(size_t)(row0 + r0) * 1024 + k0 + cb0], &As[c0 * 8]);
        gload_lds16(&Bt[(size_t)(col0 + r0) * 1024 + k0 + cb0], &Bs[c0 * 8]);
        gload_lds16(&A[(size_t)(row0 + r1) * 1024 + k0 + cb1], &As[c1 * 8]);
        gload_lds16(&Bt[(size_t)(col0 + r1) * 1024 + k0 + cb1], &Bs[c1 * 8]);
        __syncthreads();
        f16x8 af[4], bf[4];
#pragma unroll
        for (int m = 0; m < 4; ++m) af[m] = *(const f16x8*)&As[(wr * 64 + m * 16 + lr) * 32 + lg * 8];
#pragma unroll
        for (int n = 0; n < 4; ++n) bf[n] = *(const f16x8*)&Bs[(wc * 64 + n * 16 + lr) * 32 + lg * 8];
#pragma unroll
        for (int m = 0; m < 4; ++m)
#pragma unroll
            for (int n = 0; n < 4; ++n) acc[m][n] = MFMA(af[m], bf[n], acc[m][n]);
    }

#pragma unroll
    for (int m = 0; m < 4; ++m) {
#pragma unroll
        for (int n = 0; n < 4; ++n) {
            int col = col0 + wc * 64 + n * 16 + lr;
            float bv = bias[col];
#pragma unroll
            for (int r = 0; r < 4; ++r) {
                int row = row0 + wr * 64 + m * 16 + lg * 4 + r;
                Cout[(size_t)row * 1024 + col] = acc[m][n][r] + bv;
            }
        }
    }
}

// ------------------------------ attention -----------------------------------
// LDS-staged, lane-major fragments (0 bank conflicts, round 14). NEW: 4-buffer
// staging with ONE barrier per 2 tiles (round-14 diagnosis: elapsed ~3450
// cy/iter vs ~1750 cy of pipe work — the per-tile __syncthreads vmcnt(0)
// drain + 4-wave convergence was the stall). Pair loop: stage tiles t+2,t+3
// at pair start (they have 2 full tiles of compute to land before the drain),
// compute tiles t,t+1 from buffers staged one pair ago, barrier once.
// s_setprio REMOVED: block is barrier-synced lockstep = m190's regime where
// setprio measured negative. Compute body is a textual macro (no lambdas /
// pointer-passed register arrays — round-9 spill lesson).
#define ATTN_TILE(Kc, Vc)                                                     \
    do {                                                                      \
        f16x8 ka0 = *(const f16x8*)&(Kc)[fo];                                 \
        f16x8 ka1 = *(const f16x8*)&(Kc)[fo + 1024];                          \
        f16x8 ka2 = *(const f16x8*)&(Kc)[fo + 512];                           \
        f16x8 ka3 = *(const f16x8*)&(Kc)[fo + 1536];                          \
        f32x4 st[2][2];                                                       \
        _Pragma("unroll")                                                     \
        for (int qt = 0; qt < 2; ++qt) {                                      \
            float nm = -m_r[qt];                                              \
            f32x4 z = (f32x4){nm, nm, nm, nm};                                \
            z = MFMA(ka0, qf[qt][0], z);                                      \
            z = MFMA(ka1, qf[qt][1], z);                                      \
            st[qt][0] = z;                                                    \
            f32x4 z2 = (f32x4){nm, nm, nm, nm};                               \
            z2 = MFMA(ka2, qf[qt][0], z2);                                    \
            z2 = MFMA(ka3, qf[qt][1], z2);                                    \
            st[qt][1] = z2;                                                   \
        }                                                                     \
        f16x8 vv0 = *(const f16x8*)&(Vc)[fo];                                 \
        f16x8 vv1 = *(const f16x8*)&(Vc)[fo + 512];                           \
        f16x8 vv2 = *(const f16x8*)&(Vc)[fo + 1024];                          \
        f16x8 vv3 = *(const f16x8*)&(Vc)[fo + 1536];                          \
        {                                                                     \
            float lm[2];                                                      \
            _Pragma("unroll")                                                 \
            for (int qt = 0; qt < 2; ++qt) {                                  \
                float a0 = fmaxf(fmaxf(st[qt][0][0], st[qt][0][1]), st[qt][0][2]); \
                float b0 = fmaxf(fmaxf(st[qt][0][3], st[qt][1][0]), st[qt][1][1]); \
                float c0 = fmaxf(fmaxf(st[qt][1][2], st[qt][1][3]), a0);      \
                lm[qt] = fmaxf(b0, c0);                                       \
            }                                                                 \
            if (__any((lm[0] > THR) || (lm[1] > THR))) {                      \
                _Pragma("unroll")                                             \
                for (int qt = 0; qt < 2; ++qt) {                              \
                    float t0 = lm[qt];                                        \
                    t0 = fmaxf(t0, __shfl_xor(t0, 16, 64));                   \
                    t0 = fmaxf(t0, __shfl_xor(t0, 32, 64));                   \
                    float delta = fmaxf(0.f, t0);                             \
                    float alpha = __builtin_amdgcn_exp2f(-delta);             \
                    _Pragma("unroll")                                         \
                    for (int m = 0; m < 4; ++m)                               \
                        _Pragma("unroll")                                     \
                        for (int r = 0; r < 4; ++r) o[qt][m][r] *= alpha;     \
                    l_p[qt] *= alpha;                                         \
                    m_r[qt] += delta;                                         \
                    _Pragma("unroll")                                         \
                    for (int t = 0; t < 2; ++t)                               \
                        _Pragma("unroll")                                     \
                        for (int r = 0; r < 4; ++r) st[qt][t][r] -= delta;    \
                }                                                             \
            }                                                                 \
        }                                                                     \
        f16x8 pf[2];                                                          \
        _Pragma("unroll")                                                     \
        for (int qt = 0; qt < 2; ++qt) {                                      \
            float ps = 0.f;                                                   \
            union { uint32_t u[4]; f16x8 v; } bb;                             \
            _Pragma("unroll")                                                 \
            for (int t = 0; t < 2; ++t)                                       \
                _Pragma("unroll")                                             \
                for (int pr = 0; pr < 2; ++pr) {                              \
                    float e0 = __builtin_amdgcn_exp2f(st[qt][t][2 * pr]);     \
                    float e1 = __builtin_amdgcn_exp2f(st[qt][t][2 * pr + 1]); \
                    ps += e0 + e1;                                            \
                    auto hp = __builtin_amdgcn_cvt_pkrtz(e0, e1);             \
                    bb.u[t * 2 + pr] = __builtin_bit_cast(uint32_t, hp);      \
                }                                                             \
            l_p[qt] += ps;                                                    \
            pf[qt] = bb.v;                                                    \
        }                                                                     \
        _Pragma("unroll")                                                     \
        for (int qt = 0; qt < 2; ++qt) {                                      \
            o[qt][0] = MFMA(vv0, pf[qt], o[qt][0]);                           \
            o[qt][1] = MFMA(vv1, pf[qt], o[qt][1]);                           \
            o[qt][2] = MFMA(vv2, pf[qt], o[qt][2]);                           \
            o[qt][3] = MFMA(vv3, pf[qt], o[qt][3]);                           \
        }                                                                     \
    } while (0)

__global__ __launch_bounds__(256, 4) void k_attn(const f16* __restrict__ q,
                                                 const f16* __restrict__ k2,
                                                 const f16* __restrict__ v2,
                                                 f16* __restrict__ cat) {
    const int g = blockIdx.x;                 // 0..1023
    const int xcd = g & 7, i = g >> 3;        // i: 0..127
    const int bh = xcd * 8 + (i >> 4);        // 8 bh per XCD (K/V L2 locality)
    const int qb = i & 15;                    // 16 q-blocks of 128 rows
    const int b = bh >> 4, h = bh & 15;

    const int tid = threadIdx.x, wid = tid >> 6, lane = tid & 63;
    const int lr = lane & 15, lg = lane >> 4;
    const int qw = qb * 128 + wid * 32;       // this wave's first q-row

    __shared__ f16 Ks[4][2048];
    __shared__ f16 Vs[4][2048];

    const float THR = 8.0f;

    // Q fragments (hoisted; pre-scaled by 1/8*log2e in the q GEMM)
    f16x8 qf[2][2];
#pragma unroll
    for (int qt = 0; qt < 2; ++qt)
#pragma unroll
        for (int hf = 0; hf < 2; ++hf)
            qf[qt][hf] = *(const f16x8*)&q[((size_t)bh * 2048 + qw + qt * 16 + lr) * 64 + hf * 32 + lg * 8];

    const f16* kt = k2 + (size_t)bh * 131072;     // tile stride 2048 elements
    const f16* vt = v2 + (size_t)bh * 131072;
    const int so = tid * 8;                       // stage offset (16B/thread)
    const int fo = lane * 8;                      // lane-major fragment offset

    f32x4 o[2][4];
#pragma unroll
    for (int qt = 0; qt < 2; ++qt)
#pragma unroll
        for (int m = 0; m < 4; ++m) o[qt][m] = (f32x4){0.f, 0.f, 0.f, 0.f};
    float m_r[2] = {0.f, 0.f}, l_p[2] = {0.f, 0.f};

    // prologue: stage tiles 0,1 into buffers 0,1
    gload_lds16(kt + so, &Ks[0][so]);
    gload_lds16(vt + so, &Vs[0][so]);
    gload_lds16(kt + 2048 + so, &Ks[1][so]);
    gload_lds16(vt + 2048 + so, &Vs[1][so]);
    __syncthreads();

    // pair loop: tiles (2pp, 2pp+1); stage (2pp+2, 2pp+3); ONE barrier per pair
    for (int pp = 0; pp < 32; ++pp) {
        const int t0 = 2 * pp;
        const int ba = t0 & 3, bb2 = (t0 + 1) & 3;
        const int bc = (t0 + 2) & 3, bd = (t0 + 3) & 3;

        // stage next pair (pp=31 reads 2 tiles past this bh's kb2/vb2 range:
        // next-bh data / adjacent ws buffer — in-bounds of d_ws, never consumed)
        gload_lds16(kt + (size_t)(t0 + 2) * 2048 + so, &Ks[bc][so]);
        gload_lds16(vt + (size_t)(t0 + 2) * 2048 + so, &Vs[bc][so]);
        gload_lds16(kt + (size_t)(t0 + 3) * 2048 + so, &Ks[bd][so]);
        gload_lds16(vt + (size_t)(t0 + 3) * 2048 + so, &Vs[bd][so]);

        ATTN_TILE(&Ks[ba][0], &Vs[ba][0]);
        ATTN_TILE(&Ks[bb2][0], &Vs[bb2][0]);

        __syncthreads();   // buffer handoff: drains stage (covered by 2 tiles)
    }

    // epilogue: reduce per-lane l partials, normalize, store
#pragma unroll
    for (int qt = 0; qt < 2; ++qt) {
        float l = l_p[qt];
        l += __shfl_xor(l, 16, 64);
        l += __shfl_xor(l, 32, 64);
        float inv = 1.f / l;
        size_t cb = ((size_t)b * 2048 + qw + qt * 16 + lr) * 1024 + h * 64 + lg * 4;
#pragma unroll
        for (int m = 0; m < 4; ++m) {
            f16x4 ov;
#pragma unroll
            for (int r = 0; r < 4; ++r) ov[r] = (f16)(o[qt][m][r] * inv);
            *(f16x4*)&cat[cb + m * 16] = ov;
        }
    }
}

// ---------------------------------------------------------------------------
extern "C" void kernel_launch(void* const* d_in, const int* in_sizes, int n_in,
                              void* d_out, int out_size, void* d_ws, size_t ws_size,
                              hipStream_t stream) {
    const float* Q  = (const float*)d_in[0];
    const float* K  = (const float*)d_in[1];
    const float* V  = (const float*)d_in[2];
    const float* Wq = (const float*)d_in[3];
    const float* bq = (const float*)d_in[4];
    const float* Wk = (const float*)d_in[5];
    const float* bk = (const float*)d_in[6];
    const float* Wv = (const float*)d_in[7];
    const float* bv = (const float*)d_in[8];
    const float* Wo = (const float*)d_in[9];
    const float* bo = (const float*)d_in[10];

    char* ws = (char*)d_ws;
    size_t off = 0;
    auto alloc = [&](size_t bytes) {
        char* p = ws + off;
        off += (bytes + 255) & ~(size_t)255;
        return p;
    };
    f16* Qh  = (f16*)alloc(8192ULL * 1024 * 2);
    f16* Kh  = (f16*)alloc(8192ULL * 1024 * 2);
    f16* Vh  = (f16*)alloc(8192ULL * 1024 * 2);
    f16* WT  = (f16*)alloc(3ULL * 1024 * 1024 * 2);   // WqT|WkT|WvT contiguous
    f16* WoT = (f16*)alloc(1024ULL * 1024 * 2);
    f16* qb  = (f16*)alloc(8192ULL * 1024 * 2);   // head-major [(b,h)][s][64]
    f16* kb2 = (f16*)alloc(8192ULL * 1024 * 2);   // [bh][tile] lane-major perm K
    f16* vb2 = (f16*)alloc(8192ULL * 1024 * 2);   // [bh][tile] lane-major V^T
    f16* cat = (f16*)alloc(8192ULL * 1024 * 2);   // [B*S][H*VS]

    k_convert3<<<6144, 256, 0, stream>>>(Q, K, V, Qh, Kh, Vh);
    k_transpose_all<<<1024, 256, 0, stream>>>(Wq, Wk, Wv, Wo, WT, WoT);

    const float SC = 0.125f * 1.44269504089f;   // 1/sqrt(64) * log2(e), folded into q
    k_gemm_qkv<<<dim3(64, 24), 256, 0, stream>>>(Qh, Kh, Vh, WT, bq, bk, bv,
                                                 qb, kb2, vb2, SC);

    k_attn<<<1024, 256, 0, stream>>>(qb, kb2, vb2, cat);

    k_gemm_out<<<dim3(64, 8), 256, 0, stream>>>(cat, WoT, bo, (float*)d_out);
}

// Round 17
// 202.912 us; speedup vs baseline: 1.0457x; 1.0426x over previous
//
#include <hip/hip_runtime.h>
#include <hip/hip_fp16.h>
#include <cstdint>
#include <cstddef>

typedef _Float16 f16;
typedef _Float16 f16x8 __attribute__((ext_vector_type(8)));
typedef _Float16 f16x4 __attribute__((ext_vector_type(4)));
typedef float    f32x4 __attribute__((ext_vector_type(4)));

#define MFMA(a, b, c) __builtin_amdgcn_mfma_f32_16x16x32_f16(a, b, c, 0, 0, 0)

// B=4, S=2048, D=1024, H=16, KS=VS=64, O=1024.

__device__ __forceinline__ void gload_lds16(const f16* g, f16* l) {
    __builtin_amdgcn_global_load_lds(
        (const __attribute__((address_space(1))) void*)g,
        (__attribute__((address_space(3))) void*)l, 16, 0, 0);
}

// ------------------- fp32 -> fp16 convert (Q,K,V fused) ----------------------
__global__ void k_convert3(const float* __restrict__ Q, const float* __restrict__ K,
                           const float* __restrict__ V, f16* __restrict__ Qh,
                           f16* __restrict__ Kh, f16* __restrict__ Vh) {
    const int seg = blockIdx.x >> 11;              // 0..2 (2048 blocks each)
    const int lb  = blockIdx.x & 2047;
    const float* src = seg == 0 ? Q : (seg == 1 ? K : V);
    f16* dst = seg == 0 ? Qh : (seg == 1 ? Kh : Vh);
    int i = lb * blockDim.x + threadIdx.x;
    for (; i < 2097152; i += 524288) {             // n4 = 8192*1024/4
        float4 v = ((const float4*)src)[i];
        f16x4 h;
        h[0] = (f16)v.x; h[1] = (f16)v.y; h[2] = (f16)v.z; h[3] = (f16)v.w;
        ((f16x4*)dst)[i] = h;
    }
}

// ---------------- weight transpose + convert to fp16 (all 4 fused) ----------
// widx 0,1,2: W[H=16][D=1024][KS=64] -> WT + widx*1M, rows n=h*64+ks, cols d
// widx 3:     Wo[K=1024][N=1024]     -> WoT[n][k]
__global__ void k_transpose_all(const float* __restrict__ Wq, const float* __restrict__ Wk,
                                const float* __restrict__ Wv, const float* __restrict__ Wo,
                                f16* __restrict__ WT, f16* __restrict__ WoT) {
    __shared__ float T[64][65];
    const int bx = blockIdx.x;
    const int widx = bx >> 8, sub = bx & 255;
    const int nb = sub >> 4, db = sub & 15;
    const int tid = threadIdx.x;
    const float* W = widx == 0 ? Wq : (widx == 1 ? Wk : (widx == 2 ? Wv : Wo));
    f16* Wt = (widx < 3) ? (WT + (size_t)widx * 1048576) : WoT;
    const float* src = (widx < 3) ? (W + nb * 65536 + db * 4096)
                                  : (W + db * 65536 + nb * 64);
    const int rstride = (widx < 3) ? 64 : 1024;
    {
        int nn = tid & 63, d0 = tid >> 6;
#pragma unroll
        for (int p = 0; p < 16; ++p) {
            int dd = p * 4 + d0;
            T[dd][nn] = src[dd * rstride + nn];
        }
    }
    __syncthreads();
    {
        int dd = tid & 63, n0 = tid >> 6;
#pragma unroll
        for (int p = 0; p < 16; ++p) {
            int nn = p * 4 + n0;
            Wt[(size_t)(nb * 64 + nn) * 1024 + db * 64 + dd] = (f16)T[dd][nn];
        }
    }
}

// ---------------------- 256x128-tile GEMM building blocks --------------------
// LDS chunk layout (16B chunks): chunk(row, cc) = (row>>3)*68 + (row&7)*8 + cc
//  - stage: one 8-row group per wave-instr -> dest affine in lane (gload_lds ok),
//    global reads 128B-contiguous per 8 lanes (coalesced)
//  - frag reads: slot = 8*((m+lr)&3) + 4*hi + 4*kk + lg covers all 32 bank
//    slots exactly 2x -> conflict-free (2-way is free, m136)
// A tile 256x64: 32 groups * 68 chunks = 2176 chunks (34816 B)
// B tile 128x64: 16 groups * 68 chunks = 1088 chunks (17408 B)
// 3 buffers (52224 B each) = 156672 B LDS; 1 block/CU, 8 waves.
// Pipeline: STAGE(t+1) -> vmcnt(6) [own stage(t) landed] -> raw s_barrier
// [ALL waves' stage(t) landed] -> ds_read+MFMA buf(t). 3 buffers make the
// stage-write WAR safe: buf(t+1) was last read at t-2, behind the t-1 barrier.
#define G256_STAGE(AD, BD, ASRC, BSRC, KT)                                      \
    do {                                                                        \
        int ktc = (KT);                                                         \
        _Pragma("unroll")                                                       \
        for (int i2 = 0; i2 < 4; ++i2) {                                        \
            int gA = wid * 4 + i2;                      /* 0..31: 8-row group */ \
            gload_lds16(&(ASRC)[(size_t)(row0 + gA * 8 + (lane >> 3)) * 1024    \
                                + ktc * 64 + (lane & 7) * 8],                   \
                        &(AD)[(gA * 68 + lane) * 8]);                           \
        }                                                                       \
        _Pragma("unroll")                                                       \
        for (int i2 = 0; i2 < 2; ++i2) {                                        \
            int gB = wid * 2 + i2;                      /* 0..15 */             \
            gload_lds16(&(BSRC)[(size_t)(col0 + gB * 8 + (lane >> 3)) * 1024    \
                                + ktc * 64 + (lane & 7) * 8],                   \
                        &(BD)[(gB * 68 + lane) * 8]);                           \
        }                                                                       \
    } while (0)

#define G256_COMPUTE(AB, BB)                                                    \
    do {                                                                        \
        _Pragma("unroll")                                                       \
        for (int kk = 0; kk < 2; ++kk) {                                        \
            f16x8 af[4], bf[4];                                                 \
            _Pragma("unroll")                                                   \
            for (int m = 0; m < 4; ++m) {                                       \
                int rw = wm * 64 + m * 16 + lr;                                 \
                af[m] = *(const f16x8*)&(AB)[((rw >> 3) * 68 + (rw & 7) * 8     \
                                              + kk * 4 + lg) * 8];              \
            }                                                                   \
            _Pragma("unroll")                                                   \
            for (int n = 0; n < 4; ++n) {                                       \
                int rw = wn * 64 + n * 16 + lr;                                 \
                bf[n] = *(const f16x8*)&(BB)[((rw >> 3) * 68 + (rw & 7) * 8     \
                                              + kk * 4 + lg) * 8];              \
            }                                                                   \
            _Pragma("unroll")                                                   \
            for (int m = 0; m < 4; ++m)                                         \
                _Pragma("unroll")                                               \
                for (int n = 0; n < 4; ++n)                                     \
                    acc[m][n] = MFMA(af[m], bf[n], acc[m][n]);                  \
        }                                                                       \
    } while (0)

#define G256_PIPELINE(ASRC, BSRC)                                              \
    int cur = 0, nx1 = 1, nx2 = 2;                                             \
    G256_STAGE(As3, Bs3, ASRC, BSRC, 0);                                       \
    for (int t = 0; t < 16; ++t) {                                             \
        int tn = t < 15 ? t + 1 : 15;                                          \
        G256_STAGE(As3 + nx1 * 17408, Bs3 + nx1 * 8704, ASRC, BSRC, tn);       \
        asm volatile("s_waitcnt vmcnt(6)" ::: "memory");                       \
        __builtin_amdgcn_sched_barrier(0);                                     \
        __builtin_amdgcn_s_barrier();                                          \
        __builtin_amdgcn_sched_barrier(0);                                     \
        const f16* Ab = As3 + cur * 17408;                                     \
        const f16* Bb = Bs3 + cur * 8704;                                      \
        G256_COMPUTE(Ab, Bb);                                                  \
        int tmp = cur; cur = nx1; nx1 = nx2; nx2 = tmp;                        \
    }

// --------------------------- fused q/k/v GEMM (256x128) ----------------------
// grid (32, 24): y -> seg = y>>3 (0=q,1=k,2=v), col-block = y&7 (128 wide).
// Epilogues identical to the verified 128^2 versions (formulas depend only on
// rowb/col): seg0 q head-major *SC; seg1 K lane-major permuted pack;
// seg2 V^T lane-major pack.
__global__ __launch_bounds__(512, 1) void k_gemm_qkv256(
    const f16* __restrict__ Qh, const f16* __restrict__ Kh, const f16* __restrict__ Vh,
    const f16* __restrict__ WT, const float* __restrict__ bq,
    const float* __restrict__ bk, const float* __restrict__ bv,
    f16* __restrict__ qout, f16* __restrict__ kout, f16* __restrict__ vout, float SC) {
    __shared__ f16 As3[3 * 17408];   // 3 x 2176 chunks (x8 f16)
    __shared__ f16 Bs3[3 * 8704];    // 3 x 1088 chunks
    const int yy = blockIdx.y;
    const int seg = yy >> 3;
    const f16* A    = seg == 0 ? Qh : (seg == 1 ? Kh : Vh);
    const f16* Bt   = WT + (size_t)seg * 1048576;
    const float* bias = seg == 0 ? bq : (seg == 1 ? bk : bv);
    const float scale = seg == 0 ? SC : 1.0f;

    const int tid = threadIdx.x;
    const int wid = tid >> 6, lane = tid & 63;
    const int wm = wid >> 1, wn = wid & 1;          // 4M x 2N waves, 64x64 each
    const int lr = lane & 15, lg = lane >> 4;
    const int row0 = blockIdx.x * 256, col0 = (yy & 7) * 128;

    f32x4 acc[4][4];
#pragma unroll
    for (int m = 0; m < 4; ++m)
#pragma unroll
        for (int n = 0; n < 4; ++n) acc[m][n] = (f32x4){0.f, 0.f, 0.f, 0.f};

    G256_PIPELINE(A, Bt)

#pragma unroll
    for (int m = 0; m < 4; ++m) {
#pragma unroll
        for (int n = 0; n < 4; ++n) {
            int col = col0 + wn * 64 + n * 16 + lr;
            float bv_ = bias[col];
            int rowb = row0 + wm * 64 + m * 16 + lg * 4;
            int srow = rowb & 2047;
            if (seg == 0) {
#pragma unroll
                for (int r = 0; r < 4; ++r) {
                    int row = rowb + r;
                    size_t a = ((size_t)((row >> 11) * 16 + (col >> 6)) * 2048 + (row & 2047)) * 64 + (col & 63);
                    qout[a] = (f16)((acc[m][n][r] + bv_) * scale);
                }
            } else if (seg == 1) {
                int ks5 = srow & 31;
                int p0 = ((ks5 >> 2) & 1) * 16 + (ks5 >> 3) * 4 + (ks5 & 3);  // p0&3 == 0
                size_t abase = (size_t)((rowb >> 11) * 16 + (col >> 6)) * 131072
                             + (size_t)(srow >> 5) * 2048
                             + (size_t)(p0 >> 4) * 512
                             + (size_t)((col & 63) >> 5) * 1024
                             + (size_t)((col & 31) >> 3) * 128
                             + (col & 7);
#pragma unroll
                for (int r = 0; r < 4; ++r)
                    kout[abase + (size_t)((p0 & 15) + r) * 8] = (f16)(acc[m][n][r] + bv_);
            } else {
                size_t a = (size_t)((rowb >> 11) * 16 + (col >> 6)) * 131072
                         + (size_t)(srow >> 5) * 2048
                         + (size_t)((col & 63) >> 4) * 512
                         + (size_t)((srow & 31) >> 3) * 128
                         + (size_t)(col & 15) * 8
                         + (srow & 7);
                f16x4 ov;
#pragma unroll
                for (int r = 0; r < 4; ++r) ov[r] = (f16)(acc[m][n][r] + bv_);
                *(f16x4*)&vout[a] = ov;
            }
        }
    }
}

// ------------------------------ output GEMM (256x128) ------------------------
__global__ __launch_bounds__(512, 1) void k_gemm_out256(const f16* __restrict__ A,
                                                        const f16* __restrict__ Bt,
                                                        const float* __restrict__ bias,
                                                        float* __restrict__ Cout) {
    __shared__ f16 As3[3 * 17408];
    __shared__ f16 Bs3[3 * 8704];
    const int tid = threadIdx.x;
    const int wid = tid >> 6, lane = tid & 63;
    const int wm = wid >> 1, wn = wid & 1;
    const int lr = lane & 15, lg = lane >> 4;
    const int row0 = blockIdx.x * 256, col0 = blockIdx.y * 128;

    f32x4 acc[4][4];
#pragma unroll
    for (int m = 0; m < 4; ++m)
#pragma unroll
        for (int n = 0; n < 4; ++n) acc[m][n] = (f32x4){0.f, 0.f, 0.f, 0.f};

    G256_PIPELINE(A, Bt)

#pragma unroll
    for (int m = 0; m < 4; ++m) {
#pragma unroll
        for (int n = 0; n < 4; ++n) {
            int col = col0 + wn * 64 + n * 16 + lr;
            float bv = bias[col];
#pragma unroll
            for (int r = 0; r < 4; ++r) {
                int row = row0 + wm * 64 + m * 16 + lg * 4 + r;
                Cout[(size_t)row * 1024 + col] = acc[m][n][r] + bv;
            }
        }
    }
}

// ------------------------------ attention (unchanged, r16) -------------------
#define ATTN_TILE(Kc, Vc)                                                     \
    do {                                                                      \
        f16x8 ka0 = *(const f16x8*)&(Kc)[fo];                                 \
        f16x8 ka1 = *(const f16x8*)&(Kc)[fo + 1024];                          \
        f16x8 ka2 = *(const f16x8*)&(Kc)[fo + 512];                           \
        f16x8 ka3 = *(const f16x8*)&(Kc)[fo + 1536];                          \
        f32x4 st[2][2];                                                       \
        _Pragma("unroll")                                                     \
        for (int qt = 0; qt < 2; ++qt) {                                      \
            float nm = -m_r[qt];                                              \
            f32x4 z = (f32x4){nm, nm, nm, nm};                                \
            z = MFMA(ka0, qf[qt][0], z);                                      \
            z = MFMA(ka1, qf[qt][1], z);                                      \
            st[qt][0] = z;                                                    \
            f32x4 z2 = (f32x4){nm, nm, nm, nm};                               \
            z2 = MFMA(ka2, qf[qt][0], z2);                                    \
            z2 = MFMA(ka3, qf[qt][1], z2);                                    \
            st[qt][1] = z2;                                                   \
        }                                                                     \
        f16x8 vv0 = *(const f16x8*)&(Vc)[fo];                                 \
        f16x8 vv1 = *(const f16x8*)&(Vc)[fo + 512];                           \
        f16x8 vv2 = *(const f16x8*)&(Vc)[fo + 1024];                          \
        f16x8 vv3 = *(const f16x8*)&(Vc)[fo + 1536];                          \
        {                                                                     \
            float lm[2];                                                      \
            _Pragma("unroll")                                                 \
            for (int qt = 0; qt < 2; ++qt) {                                  \
                float a0 = fmaxf(fmaxf(st[qt][0][0], st[qt][0][1]), st[qt][0][2]); \
                float b0 = fmaxf(fmaxf(st[qt][0][3], st[qt][1][0]), st[qt][1][1]); \
                float c0 = fmaxf(fmaxf(st[qt][1][2], st[qt][1][3]), a0);      \
                lm[qt] = fmaxf(b0, c0);                                       \
            }                                                                 \
            if (__any((lm[0] > THR) || (lm[1] > THR))) {                      \
                _Pragma("unroll")                                             \
                for (int qt = 0; qt < 2; ++qt) {                              \
                    float t0 = lm[qt];                                        \
                    t0 = fmaxf(t0, __shfl_xor(t0, 16, 64));                   \
                    t0 = fmaxf(t0, __shfl_xor(t0, 32, 64));                   \
                    float delta = fmaxf(0.f, t0);                             \
                    float alpha = __builtin_amdgcn_exp2f(-delta);             \
                    _Pragma("unroll")                                         \
                    for (int m = 0; m < 4; ++m)                               \
                        _Pragma("unroll")                                     \
                        for (int r = 0; r < 4; ++r) o[qt][m][r] *= alpha;     \
                    l_p[qt] *= alpha;                                         \
                    m_r[qt] += delta;                                         \
                    _Pragma("unroll")                                         \
                    for (int t = 0; t < 2; ++t)                               \
                        _Pragma("unroll")                                     \
                        for (int r = 0; r < 4; ++r) st[qt][t][r] -= delta;    \
                }                                                             \
            }                                                                 \
        }                                                                     \
        f16x8 pf[2];                                                          \
        _Pragma("unroll")                                                     \
        for (int qt = 0; qt < 2; ++qt) {                                      \
            float ps = 0.f;                                                   \
            union { uint32_t u[4]; f16x8 v; } bb;                             \
            _Pragma("unroll")                                                 \
            for (int t = 0; t < 2; ++t)                                       \
                _Pragma("unroll")                                             \
                for (int pr = 0; pr < 2; ++pr) {                              \
                    float e0 = __builtin_amdgcn_exp2f(st[qt][t][2 * pr]);     \
                    float e1 = __builtin_amdgcn_exp2f(st[qt][t][2 * pr + 1]); \
                    ps += e0 + e1;                                            \
                    auto hp = __builtin_amdgcn_cvt_pkrtz(e0, e1);             \
                    bb.u[t * 2 + pr] = __builtin_bit_cast(uint32_t, hp);      \
                }                                                             \
            l_p[qt] += ps;                                                    \
            pf[qt] = bb.v;                                                    \
        }                                                                     \
        _Pragma("unroll")                                                     \
        for (int qt = 0; qt < 2; ++qt) {                                      \
            o[qt][0] = MFMA(vv0, pf[qt], o[qt][0]);                           \
            o[qt][1] = MFMA(vv1, pf[qt], o[qt][1]);                           \
            o[qt][2] = MFMA(vv2, pf[qt], o[qt][2]);                           \
            o[qt][3] = MFMA(vv3, pf[qt], o[qt][3]);                           \
        }                                                                     \
    } while (0)

__global__ __launch_bounds__(256, 4) void k_attn(const f16* __restrict__ q,
                                                 const f16* __restrict__ k2,
                                                 const f16* __restrict__ v2,
                                                 f16* __restrict__ cat) {
    const int g = blockIdx.x;                 // 0..1023
    const int xcd = g & 7, i = g >> 3;        // i: 0..127
    const int bh = xcd * 8 + (i >> 4);        // 8 bh per XCD (K/V L2 locality)
    const int qb = i & 15;                    // 16 q-blocks of 128 rows
    const int b = bh >> 4, h = bh & 15;

    const int tid = threadIdx.x, wid = tid >> 6, lane = tid & 63;
    const int lr = lane & 15, lg = lane >> 4;
    const int qw = qb * 128 + wid * 32;       // this wave's first q-row

    __shared__ f16 Ks[4][2048];
    __shared__ f16 Vs[4][2048];

    const float THR = 8.0f;

    f16x8 qf[2][2];
#pragma unroll
    for (int qt = 0; qt < 2; ++qt)
#pragma unroll
        for (int hf = 0; hf < 2; ++hf)
            qf[qt][hf] = *(const f16x8*)&q[((size_t)bh * 2048 + qw + qt * 16 + lr) * 64 + hf * 32 + lg * 8];

    const f16* kt = k2 + (size_t)bh * 131072;
    const f16* vt = v2 + (size_t)bh * 131072;
    const int so = tid * 8;
    const int fo = lane * 8;

    f32x4 o[2][4];
#pragma unroll
    for (int qt = 0; qt < 2; ++qt)
#pragma unroll
        for (int m = 0; m < 4; ++m) o[qt][m] = (f32x4){0.f, 0.f, 0.f, 0.f};
    float m_r[2] = {0.f, 0.f}, l_p[2] = {0.f, 0.f};

    gload_lds16(kt + so, &Ks[0][so]);
    gload_lds16(vt + so, &Vs[0][so]);
    gload_lds16(kt + 2048 + so, &Ks[1][so]);
    gload_lds16(vt + 2048 + so, &Vs[1][so]);
    __syncthreads();

    for (int pp = 0; pp < 32; ++pp) {
        const int t0 = 2 * pp;
        const int ba = t0 & 3, bb2 = (t0 + 1) & 3;
        const int bc = (t0 + 2) & 3, bd = (t0 + 3) & 3;

        gload_lds16(kt + (size_t)(t0 + 2) * 2048 + so, &Ks[bc][so]);
        gload_lds16(vt + (size_t)(t0 + 2) * 2048 + so, &Vs[bc][so]);
        gload_lds16(kt + (size_t)(t0 + 3) * 2048 + so, &Ks[bd][so]);
        gload_lds16(vt + (size_t)(t0 + 3) * 2048 + so, &Vs[bd][so]);

        ATTN_TILE(&Ks[ba][0], &Vs[ba][0]);
        ATTN_TILE(&Ks[bb2][0], &Vs[bb2][0]);

        __syncthreads();
    }

#pragma unroll
    for (int qt = 0; qt < 2; ++qt) {
        float l = l_p[qt];
        l += __shfl_xor(l, 16, 64);
        l += __shfl_xor(l, 32, 64);
        float inv = 1.f / l;
        size_t cb = ((size_t)b * 2048 + qw + qt * 16 + lr) * 1024 + h * 64 + lg * 4;
#pragma unroll
        for (int m = 0; m < 4; ++m) {
            f16x4 ov;
#pragma unroll
            for (int r = 0; r < 4; ++r) ov[r] = (f16)(o[qt][m][r] * inv);
            *(f16x4*)&cat[cb + m * 16] = ov;
        }
    }
}

// ---------------------------------------------------------------------------
extern "C" void kernel_launch(void* const* d_in, const int* in_sizes, int n_in,
                              void* d_out, int out_size, void* d_ws, size_t ws_size,
                              hipStream_t stream) {
    const float* Q  = (const float*)d_in[0];
    const float* K  = (const float*)d_in[1];
    const float* V  = (const float*)d_in[2];
    const float* Wq = (const float*)d_in[3];
    const float* bq = (const float*)d_in[4];
    const float* Wk = (const float*)d_in[5];
    const float* bk = (const float*)d_in[6];
    const float* Wv = (const float*)d_in[7];
    const float* bv = (const float*)d_in[8];
    const float* Wo = (const float*)d_in[9];
    const float* bo = (const float*)d_in[10];

    char* ws = (char*)d_ws;
    size_t off = 0;
    auto alloc = [&](size_t bytes) {
        char* p = ws + off;
        off += (bytes + 255) & ~(size_t)255;
        return p;
    };
    f16* Qh  = (f16*)alloc(8192ULL * 1024 * 2);
    f16* Kh  = (f16*)alloc(8192ULL * 1024 * 2);
    f16* Vh  = (f16*)alloc(8192ULL * 1024 * 2);
    f16* WT  = (f16*)alloc(3ULL * 1024 * 1024 * 2);   // WqT|WkT|WvT contiguous
    f16* WoT = (f16*)alloc(1024ULL * 1024 * 2);
    f16* qb  = (f16*)alloc(8192ULL * 1024 * 2);   // head-major [(b,h)][s][64]
    f16* kb2 = (f16*)alloc(8192ULL * 1024 * 2);   // [bh][tile] lane-major perm K
    f16* vb2 = (f16*)alloc(8192ULL * 1024 * 2);   // [bh][tile] lane-major V^T
    f16* cat = (f16*)alloc(8192ULL * 1024 * 2);   // [B*S][H*VS]

    k_convert3<<<6144, 256, 0, stream>>>(Q, K, V, Qh, Kh, Vh);
    k_transpose_all<<<1024, 256, 0, stream>>>(Wq, Wk, Wv, Wo, WT, WoT);

    const float SC = 0.125f * 1.44269504089f;   // 1/sqrt(64) * log2(e), folded into q
    k_gemm_qkv256<<<dim3(32, 24), 512, 0, stream>>>(Qh, Kh, Vh, WT, bq, bk, bv,
                                                    qb, kb2, vb2, SC);

    k_attn<<<1024, 256, 0, stream>>>(qb, kb2, vb2, cat);

    k_gemm_out256<<<dim3(32, 8), 512, 0, stream>>>(cat, WoT, bo, (float*)d_out);
}